// Round 1
// baseline (162.797 us; speedup 1.0000x reference)
//
#include <hip/hip_runtime.h>
#include <hip/hip_bf16.h>

typedef __bf16 bf16x8 __attribute__((ext_vector_type(8)));
typedef float f32x4 __attribute__((ext_vector_type(4)));
typedef unsigned int u32;
typedef unsigned short u16;
typedef u32 u32x4 __attribute__((ext_vector_type(4)));
typedef u16 u16x4 __attribute__((ext_vector_type(4)));

// round-to-nearest-even f32 -> bf16
__device__ __forceinline__ u16 f2bf(float x) {
  u32 u = __float_as_uint(x);
  return (u16)((u + 0x7FFFu + ((u >> 16) & 1u)) >> 16);
}

__device__ __forceinline__ bf16x8 ld_frag_lds(const u16* base, int byteOff) {
  u32x4 v = *(const u32x4*)((const char*)base + byteOff);
  return __builtin_bit_cast(bf16x8, v);
}

__device__ __forceinline__ bf16x8 ld_frag_glb(const u16* p) {
  u32x4 v = *(const u32x4*)p;
  return __builtin_bit_cast(bf16x8, v);
}

// ---------------------------------------------------------------------------
// Prep: convert W2a [256x256] f32 and W2b [256x64] f32 into bf16 fragments
// laid out in the exact per-lane order GEMM loads them:
//   wfA[((ntg*8 + ks)*64 + lane)*8 + q] = W2a[ks*32 + (lane>>4)*8 + q][ntg*16 + (lane&15)]
// ---------------------------------------------------------------------------
__global__ void prep_kernel(const float* __restrict__ W2a, const float* __restrict__ W2b,
                            u16* __restrict__ wfA, u16* __restrict__ wfB) {
  int t = blockIdx.x * 256 + threadIdx.x;
  if (t < 8192) {  // 16 ntiles * 8 ksteps * 64 lanes
    int lane = t & 63;
    int ks = (t >> 6) & 7;
    int ntg = t >> 9;  // 0..15
    int col = (ntg << 4) + (lane & 15);
    int kb = (ks << 5) + ((lane >> 4) << 3);
#pragma unroll
    for (int q = 0; q < 8; ++q)
      wfA[t * 8 + q] = f2bf(W2a[(kb + q) * 256 + col]);
  } else if (t < 10240) {  // 4 ntiles * 8 ksteps * 64 lanes
    int t2 = t - 8192;
    int lane = t2 & 63;
    int ks = (t2 >> 6) & 7;
    int ntg = t2 >> 9;  // 0..3
    int col = (ntg << 4) + (lane & 15);
    int kb = (ks << 5) + ((lane >> 4) << 3);
#pragma unroll
    for (int q = 0; q < 8; ++q)
      wfB[t2 * 8 + q] = f2bf(W2b[(kb + q) * 64 + col]);
  }
}

// ---------------------------------------------------------------------------
// out1: per (b,i): max/min reduce emb2[b,i,:,:] over j, cat with emb1,
// then the small MLP (192->128 relu ->64), all f32. One block per (b,i).
// ---------------------------------------------------------------------------
__global__ __launch_bounds__(256) void out1_kernel(
    const float* __restrict__ emb1, const float* __restrict__ emb2,
    const float* __restrict__ W1a, const float* __restrict__ b1a,
    const float* __restrict__ W1b, const float* __restrict__ b1b,
    float* __restrict__ out1) {
  int bi = blockIdx.x;  // b*256 + i
  int t = threadIdx.x;
  __shared__ float smax[4][64];
  __shared__ float smin[4][64];
  __shared__ float cat1[192];
  __shared__ float h[128];

  int d = t & 63, q = t >> 6;
  const float* base = emb2 + (size_t)bi * 256 * 64;
  float vmax = -INFINITY, vmin = INFINITY;
  for (int j = q; j < 256; j += 4) {
    float v = base[j * 64 + d];
    vmax = fmaxf(vmax, v);
    vmin = fminf(vmin, v);
  }
  smax[q][d] = vmax;
  smin[q][d] = vmin;
  __syncthreads();
  if (t < 64) {
    float mx = fmaxf(fmaxf(smax[0][t], smax[1][t]), fmaxf(smax[2][t], smax[3][t]));
    float mn = fminf(fminf(smin[0][t], smin[1][t]), fminf(smin[2][t], smin[3][t]));
    cat1[t] = emb1[bi * 64 + t];
    cat1[64 + t] = mx;
    cat1[128 + t] = mn;
  }
  __syncthreads();
  if (t < 128) {
    float acc = b1a[t];
    for (int k = 0; k < 192; ++k) acc += cat1[k] * W1a[k * 128 + t];
    h[t] = fmaxf(acc, 0.f);
  }
  __syncthreads();
  if (t < 64) {
    float acc = b1b[t];
    for (int k = 0; k < 128; ++k) acc += h[k] * W1b[k * 64 + t];
    out1[bi * 64 + t] = acc;
  }
}

// ---------------------------------------------------------------------------
// out2: one block = (b, i, j-tile of 64). Fused MLP with bf16 MFMA.
// X row r (j = j0+r) = [emb1[b,j] | emb2[b,j,i] | emb1[b,i] | emb2[b,i,j]] (256)
// LDS tiles XOR-swizzled: byte ^= (row&7)<<4  (stride 512B rows, 64KB total)
// ---------------------------------------------------------------------------
__global__ __launch_bounds__(256, 2) void out2_kernel(
    const float* __restrict__ emb1, const float* __restrict__ emb2,
    const float* __restrict__ b2a, const float* __restrict__ b2b,
    const u16* __restrict__ wfA, const u16* __restrict__ wfB,
    float* __restrict__ out2) {
  __shared__ __align__(16) u16 Xs[64 * 256];
  __shared__ __align__(16) u16 Hs[64 * 256];

  int blk = blockIdx.x;
  int b = blk >> 10;
  int i = (blk >> 2) & 255;
  int j0 = (blk & 3) << 6;
  int t = threadIdx.x;
  int lane = t & 63;
  int w = t >> 6;
  int lr = lane & 15;  // row/col within 16-tile
  int lg = lane >> 4;  // k-group

  // ---- stage X: 64 rows x 256 feats -> bf16 LDS (swizzled) ----
  {
    int r = t >> 2;
    int c0 = (t & 3) << 4;
    const float* s0 = emb1 + ((b << 8) + j0 + r) * 64;
    const float* s1 = emb2 + ((((size_t)(b << 8) + j0 + r) << 8) + i) * 64;
    const float* s2 = emb1 + ((b << 8) + i) * 64;
    const float* s3 = emb2 + ((((size_t)(b << 8) + i) << 8) + (j0 + r)) * 64;
    const float* srcs[4] = {s0, s1, s2, s3};
#pragma unroll
    for (int seg = 0; seg < 4; ++seg) {
      const float* src = srcs[seg];
#pragma unroll
      for (int u = 0; u < 4; ++u) {
        int d = c0 + (u << 2);
        float4 v = *(const float4*)(src + d);
        u16x4 o = {f2bf(v.x), f2bf(v.y), f2bf(v.z), f2bf(v.w)};
        int byteOff = (r * 512 + ((seg << 6) + d) * 2) ^ ((r & 7) << 4);
        *(u16x4*)((char*)Xs + byteOff) = o;
      }
    }
  }
  __syncthreads();

  // ---- GEMM1: H(64x256) = relu(X @ W2a + b2a); wave w owns cols [w*64, w*64+64) ----
  f32x4 acc1[4][4];
#pragma unroll
  for (int m = 0; m < 4; ++m)
#pragma unroll
    for (int nt = 0; nt < 4; ++nt) acc1[m][nt] = (f32x4){0.f, 0.f, 0.f, 0.f};

#pragma unroll
  for (int ks = 0; ks < 8; ++ks) {
    int kByte = (ks << 6) + (lg << 4);  // (ks*32 + lg*8) bf16 -> bytes
    bf16x8 a[4];
#pragma unroll
    for (int m = 0; m < 4; ++m) {
      int r = (m << 4) + lr;
      int off = (r * 512 + kByte) ^ ((r & 7) << 4);
      a[m] = ld_frag_lds(Xs, off);
    }
    bf16x8 bw[4];
#pragma unroll
    for (int nt = 0; nt < 4; ++nt)
      bw[nt] = ld_frag_glb(wfA + (size_t)((((w << 2) + nt) * 8 + ks) * 64 + lane) * 8);
#pragma unroll
    for (int m = 0; m < 4; ++m)
#pragma unroll
      for (int nt = 0; nt < 4; ++nt)
        acc1[m][nt] = __builtin_amdgcn_mfma_f32_16x16x32_bf16(a[m], bw[nt], acc1[m][nt], 0, 0, 0);
  }

  // ---- bias + relu -> Hs (bf16, swizzled). C/D map: col=lane&15, row=4*(lane>>4)+e ----
#pragma unroll
  for (int nt = 0; nt < 4; ++nt) {
    int n = (w << 6) + (nt << 4) + lr;
    float bias = b2a[n];
#pragma unroll
    for (int m = 0; m < 4; ++m) {
      int r0 = (m << 4) + (lg << 2);
#pragma unroll
      for (int e = 0; e < 4; ++e) {
        int r = r0 + e;
        float hv = fmaxf(acc1[m][nt][e] + bias, 0.f);
        int off = (r * 512 + n * 2) ^ ((r & 7) << 4);
        *(u16*)((char*)Hs + off) = f2bf(hv);
      }
    }
  }
  __syncthreads();

  // ---- GEMM2: out(64x64) = H @ W2b + b2b; wave w owns cols [w*16, w*16+16) ----
  f32x4 acc2[4];
#pragma unroll
  for (int m = 0; m < 4; ++m) acc2[m] = (f32x4){0.f, 0.f, 0.f, 0.f};

#pragma unroll
  for (int ks = 0; ks < 8; ++ks) {
    int kByte = (ks << 6) + (lg << 4);
    bf16x8 bw = ld_frag_glb(wfB + (size_t)(((w << 3) + ks) * 64 + lane) * 8);
#pragma unroll
    for (int m = 0; m < 4; ++m) {
      int r = (m << 4) + lr;
      int off = (r * 512 + kByte) ^ ((r & 7) << 4);
      bf16x8 a = ld_frag_lds(Hs, off);
      acc2[m] = __builtin_amdgcn_mfma_f32_16x16x32_bf16(a, bw, acc2[m], 0, 0, 0);
    }
  }

  // ---- store out2 tile (f32) ----
  int col = (w << 4) + lr;
  float bias2 = b2b[col];
  float* obase = out2 + ((((size_t)(b << 8) + i) << 8) + j0) * 64;
#pragma unroll
  for (int m = 0; m < 4; ++m) {
    int r0 = (m << 4) + (lg << 2);
#pragma unroll
    for (int e = 0; e < 4; ++e)
      obase[(size_t)(r0 + e) * 64 + col] = acc2[m][e] + bias2;
  }
}

extern "C" void kernel_launch(void* const* d_in, const int* in_sizes, int n_in,
                              void* d_out, int out_size, void* d_ws, size_t ws_size,
                              hipStream_t stream) {
  const float* emb1 = (const float*)d_in[0];
  const float* emb2 = (const float*)d_in[1];
  const float* W1a  = (const float*)d_in[2];
  const float* b1a  = (const float*)d_in[3];
  const float* W1b  = (const float*)d_in[4];
  const float* b1b  = (const float*)d_in[5];
  const float* W2a  = (const float*)d_in[6];
  const float* b2a  = (const float*)d_in[7];
  const float* W2b  = (const float*)d_in[8];
  const float* b2b  = (const float*)d_in[9];

  float* out = (float*)d_out;
  u16* wfA = (u16*)d_ws;               // 16*8*64*8 = 65536 bf16 = 128 KB
  u16* wfB = wfA + 16 * 8 * 64 * 8;    //  4*8*64*8 = 16384 bf16 =  32 KB

  prep_kernel<<<40, 256, 0, stream>>>(W2a, W2b, wfA, wfB);
  out1_kernel<<<2048, 256, 0, stream>>>(emb1, emb2, W1a, b1a, W1b, b1b, out);
  out2_kernel<<<8192, 256, 0, stream>>>(emb1, emb2, b2a, b2b, wfA, wfB,
                                        out + 8 * 256 * 64);
}